// Round 2
// baseline (120.256 us; speedup 1.0000x reference)
//
#include <hip/hip_runtime.h>

#define BB 8
#define CC 128
#define HH 112
#define WW 112
#define GG 4
#define CGr 32       // channels per group
#define KK2 9        // K*K
#define OCG 32       // out channels per group
#define TH 16
#define TW 16
#define PITCH 20     // TW+2 padded to 20 floats: bank conflicts <= 3-way
#define HALO_H (TH + 2)
#define HALO_W (TW + 2)
#define NT 256

__global__ __launch_bounds__(NT, 2)
void invol_fused(const float* __restrict__ x,
                 const float* __restrict__ w_kg,
                 const float* __restrict__ b_kg,
                 const float* __restrict__ w_pw,
                 const float* __restrict__ b_pw,
                 float* __restrict__ out)
{
    __shared__ float xs[CGr][HALO_H][PITCH];   // 32*18*20*4 = 46,080 B -> 3 blocks/CU

    const int tile  = blockIdx.x;              // 0..48 (7x7 tiles of 16x16)
    const int tileh = tile / 7;
    const int tilew = tile - tileh * 7;
    const int g = blockIdx.y;
    const int b = blockIdx.z;
    const int h0 = tileh * TH;
    const int w0 = tilew * TW;
    const int tid = threadIdx.x;

    // ---- stage x tile (+1 halo) for this (batch, group) into LDS ----
    {
        const float* xg = x + (size_t)(b * CC + g * CGr) * (HH * WW);
        for (int i = tid; i < CGr * HALO_H * HALO_W; i += NT) {
            int c   = i / (HALO_H * HALO_W);
            int rem = i - c * (HALO_H * HALO_W);
            int r   = rem / HALO_W;
            int col = rem - r * HALO_W;
            int gh = h0 - 1 + r;
            int gw = w0 - 1 + col;
            float v = 0.0f;
            if ((unsigned)gh < (unsigned)HH && (unsigned)gw < (unsigned)WW)
                v = xg[(size_t)c * (HH * WW) + gh * WW + gw];
            xs[c][r][col] = v;
        }
    }
    __syncthreads();

    const int tx = tid & 15;
    const int ty = tid >> 4;

    // group-local weight bases: all indices below are workgroup-uniform ->
    // compiler should emit scalar (s_load) accesses, K$-cached.
    const float* wk = w_kg + (size_t)g * (KK2 * CGr * KK2);  // ((g*9+t)*32+c)*9+u
    const float* bk = b_kg + g * KK2;
    const float* wp = w_pw + (size_t)g * (OCG * CGr);        // (g*32+o)*32+c
    const float* bp = b_pw + g * OCG;

    // ---- pass 1: per-pixel dynamic kernel kv[9] (grouped 3x3 conv + bias) ----
    float kv[KK2];
    #pragma unroll
    for (int t = 0; t < KK2; ++t) kv[t] = bk[t];

    #pragma unroll 1
    for (int c = 0; c < CGr; ++c) {
        float p[3][3];
        #pragma unroll
        for (int r = 0; r < 3; ++r)
            #pragma unroll
            for (int j = 0; j < 3; ++j)
                p[r][j] = xs[c][ty + r][tx + j];
        const float* wc = wk + c * KK2;
        #pragma unroll
        for (int t = 0; t < KK2; ++t) {
            const float* wr = wc + t * (CGr * KK2);
            float a = kv[t];
            #pragma unroll
            for (int u = 0; u < KK2; ++u)
                a = fmaf(p[u / 3][u % 3], wr[u], a);
            kv[t] = a;
        }
    }

    // ---- pass 2: involution (apply kv to each channel) + grouped 1x1 conv ----
    float acc[OCG];
    #pragma unroll
    for (int o = 0; o < OCG; ++o) acc[o] = 0.0f;

    #pragma unroll 1
    for (int c = 0; c < CGr; ++c) {
        float m = 0.0f;
        #pragma unroll
        for (int r = 0; r < 3; ++r)
            #pragma unroll
            for (int j = 0; j < 3; ++j)
                m = fmaf(xs[c][ty + r][tx + j], kv[r * 3 + j], m);
        #pragma unroll
        for (int o = 0; o < OCG; ++o)
            acc[o] = fmaf(m, wp[o * CGr + c], acc[o]);
    }

    // ---- store: 32 coalesced b32 stores per thread (one per out channel) ----
    const int gh = h0 + ty;
    const int gw = w0 + tx;
    float* og = out + ((size_t)(b * CC + g * OCG) * HH + gh) * WW + gw;
    #pragma unroll
    for (int o = 0; o < OCG; ++o)
        og[(size_t)o * (HH * WW)] = acc[o] + bp[o];
}

extern "C" void kernel_launch(void* const* d_in, const int* in_sizes, int n_in,
                              void* d_out, int out_size, void* d_ws, size_t ws_size,
                              hipStream_t stream)
{
    const float* x    = (const float*)d_in[0];
    const float* w_kg = (const float*)d_in[1];
    const float* b_kg = (const float*)d_in[2];
    const float* w_pw = (const float*)d_in[3];
    const float* b_pw = (const float*)d_in[4];
    float* out = (float*)d_out;

    dim3 grid(49, GG, BB);
    dim3 block(NT);
    hipLaunchKernelGGL(invol_fused, grid, block, 0, stream,
                       x, w_kg, b_kg, w_pw, b_pw, out);
}